// Round 12
// baseline (398.333 us; speedup 1.0000x reference)
//
#include <hip/hip_runtime.h>
#include <hip/hip_bf16.h>

#define N_USERC 50000
#define N_ITEMC 100000
#define NNODE   150000
#define DIM     64
#define NLAYERS 3
#define NNZC    2400000
#define BATCH   1024

#define RPB     128                 // rows per bucket (bucket = row>>7)
#define NBUCK   1172                // ceil(150000/128)
#define NCHUNK  512
#define CHUNK   4688                // 512*4688 = 2400256 >= NNZ
#define CAPB    3072                // compact LDS staging capacity (avg 2048)
#define NPARTB  8                   // (carve kept for layout stability)

using short8 = __attribute__((ext_vector_type(8))) short;   // 8 bf16
using f32x4  = __attribute__((ext_vector_type(4))) float;   // MFMA acc
using uintx4 = __attribute__((ext_vector_type(4))) unsigned;

// ---------------------------------------------------------------------------
// helpers
// ---------------------------------------------------------------------------
__device__ __forceinline__ float bf2f(ushort u) {
    return __uint_as_float(((unsigned)u) << 16);
}
__device__ __forceinline__ ushort f2bf(float f) {
    unsigned u = __float_as_uint(f);
    u += 0x7FFF + ((u >> 16) & 1);          // RNE
    return (ushort)(u >> 16);
}

// exclusive scan of one value per thread across the block (blockDim==256)
__device__ __forceinline__ int block_excl_scan(int v, int* lds) {
    int lane = threadIdx.x & 63;
    int wid  = threadIdx.x >> 6;
    int nw   = (blockDim.x + 63) >> 6;
    int inc = v;
#pragma unroll
    for (int o = 1; o < 64; o <<= 1) {
        int n = __shfl_up(inc, o, 64);
        if (lane >= o) inc += n;
    }
    if (lane == 63) lds[wid] = inc;
    __syncthreads();
    if (wid == 0) {
        int tv = (lane < nw) ? lds[lane] : 0;
#pragma unroll
        for (int o = 1; o < 16; o <<= 1) {
            int n = __shfl_up(tv, o, 64);
            if (lane >= o) tv += n;
        }
        if (lane < nw) lds[lane] = tv;
    }
    __syncthreads();
    int woff = (wid == 0) ? 0 : lds[wid - 1];
    return woff + (inc - v);
}

// ---------------------------------------------------------------------------
// Merged prep: copy_E + INLINE user-MLP blend + prepW. winner[] inited in
// chunksort, atomicMax'd in compact (both prior dispatches). Also writes
// rowptr[NNODE]=NNZC.
// ---------------------------------------------------------------------------
__global__ __launch_bounds__(256) void k_prep(const float* __restrict__ ue,
                                              const float* __restrict__ ie,
                                              ushort* __restrict__ Ebf,
                                              const float* __restrict__ w1,
                                              const float* __restrict__ w2,
                                              ushort* __restrict__ Wtg,
                                              const float* __restrict__ user_feat,
                                              const float* __restrict__ l1w,
                                              const float* __restrict__ l1b,
                                              const float* __restrict__ l2w,
                                              const float* __restrict__ l2b,
                                              const float* __restrict__ ratio_p,
                                              const int* __restrict__ winner,
                                              int* __restrict__ rowptr) {
    int i = blockIdx.x * blockDim.x + threadIdx.x;        // float4 index
    const int userEnd = N_USERC * DIM / 4;
    const int total   = NNODE * DIM / 4;
    if (i == 0) rowptr[NNODE] = NNZC;
    if (i < total) {
        float4 v;
        if (i < userEnd) v = ((const float4*)ue)[i];
        else             v = ((const float4*)ie)[i - userEnd];
        if (i < userEnd) {
            int u = i >> 4;
            int b = winner[u];
            if (b >= 0) {                                  // blend with MLP out
                int d0 = (i & 15) * 4;
                float ratio = ratio_p[0];
                float uf0 = user_feat[b * 4 + 0], uf1 = user_feat[b * 4 + 1];
                float uf2 = user_feat[b * 4 + 2], uf3 = user_feat[b * 4 + 3];
                float a0 = l2b[d0 + 0], a1 = l2b[d0 + 1];
                float a2 = l2b[d0 + 2], a3 = l2b[d0 + 3];
#pragma unroll
                for (int j = 0; j < 32; ++j) {
                    float h = l1b[j] + uf0 * l1w[0 * 32 + j] + uf1 * l1w[1 * 32 + j]
                                     + uf2 * l1w[2 * 32 + j] + uf3 * l1w[3 * 32 + j];
                    a0 += h * l2w[j * DIM + d0 + 0];
                    a1 += h * l2w[j * DIM + d0 + 1];
                    a2 += h * l2w[j * DIM + d0 + 2];
                    a3 += h * l2w[j * DIM + d0 + 3];
                }
                float om = 1.f - ratio;
                v.x = v.x * om + a0 * ratio;
                v.y = v.y * om + a1 * ratio;
                v.z = v.z * om + a2 * ratio;
                v.w = v.w * om + a3 * ratio;
            }
        }
        ushort4 b4;
        b4.x = f2bf(v.x); b4.y = f2bf(v.y); b4.z = f2bf(v.z); b4.w = f2bf(v.w);
        ((ushort4*)Ebf)[i] = b4;
    }
    if (i < NLAYERS * 64 * 128) {                         // blocks 0..95
        int layer = i >> 13;                              // /8192
        int rem = i & 8191;
        int n = rem >> 7, kk = rem & 127;
        float v = (kk < 64) ? w1[layer * 4096 + kk * 64 + n]
                            : w2[layer * 4096 + (kk - 64) * 64 + n];
        Wtg[i] = f2bf(v);
    }
}

// ---------------------------------------------------------------------------
// Pass 1: per-chunk LDS counting sort into 128-row buckets. Streaming writes.
// packed = [ ro:7 (bits 50..56) | col:18 (bits 32..49) | val:32 ]
// Publishes offsets TRANSPOSED: scanT[bucket][chunk]. Row NBUCK = totals.
// Also initializes winner[] (atomicMax'd later in k_compact).
// ---------------------------------------------------------------------------
__global__ __launch_bounds__(256) void k_chunksort(const int* __restrict__ rows,
                                                   const int* __restrict__ cols,
                                                   const float* __restrict__ vals,
                                                   unsigned long long* __restrict__ tmp,
                                                   ushort* __restrict__ scanT,
                                                   int* __restrict__ winner) {
    __shared__ int hist[NBUCK];                 // hist -> excl scan -> cursors
    __shared__ int sutil[16];
    __shared__ unsigned long long stag[CHUNK];  // 37.5 KB

    const int c = blockIdx.x;
    const int s = c * CHUNK;
    const int e = (s + CHUNK < NNZC) ? s + CHUNK : NNZC;
    const int t = threadIdx.x;

    // winner init (consumed by k_compact's atomicMax, a later dispatch)
    for (int i = c * 256 + t; i < N_USERC; i += NCHUNK * 256) winner[i] = -1;

    for (int i = t; i < NBUCK; i += 256) hist[i] = 0;
    __syncthreads();
    for (int i = s + t; i < e; i += 256) atomicAdd(&hist[rows[i] >> 7], 1);
    __syncthreads();

    // scan 1172 counters: 5 entries per thread
    int loc[5];
    int sum = 0;
#pragma unroll
    for (int k = 0; k < 5; ++k) {
        int idx = t * 5 + k;
        int v = (idx < NBUCK) ? hist[idx] : 0;
        loc[k] = sum;
        sum += v;
    }
    int excl = block_excl_scan(sum, sutil);
#pragma unroll
    for (int k = 0; k < 5; ++k) {
        int idx = t * 5 + k;
        if (idx < NBUCK) hist[idx] = excl + loc[k];
    }
    __syncthreads();

    // publish per-chunk offsets (exclusive) TRANSPOSED; totals in row NBUCK
    for (int i = t; i < NBUCK; i += 256) scanT[(size_t)i * NCHUNK + c] = (ushort)hist[i];
    if (t == 0) scanT[(size_t)NBUCK * NCHUNK + c] = (ushort)(e - s);
    __syncthreads();

    // scatter into LDS staging via cursors
    for (int i = s + t; i < e; i += 256) {
        int r = rows[i];
        int b = r >> 7, ro = r & 127;
        unsigned hi = ((unsigned)ro << 18) | (unsigned)cols[i];
        unsigned long long pk = ((unsigned long long)hi << 32) | (unsigned)__float_as_uint(vals[i]);
        int pos = atomicAdd(&hist[b], 1);
        stag[pos] = pk;
    }
    __syncthreads();

    // streaming write-back (full lines)
    int n = e - s;
    for (int i = t; i < n; i += 256) tmp[s + i] = stag[i];
}

// Pass 2: compact runs into bucket-contiguous, ROW-SORTED csr + rowptr.
// obase computed IN-BLOCK: Sigma_c scanT[b][c]. Block 0 also does the
// winner atomicMax side-job. R12: staging is ELEMENT-PARALLEL via an LDS
// run-map — the old thread-per-run loop serialized ~26 dependent global-
// latency steps per wave; the map-fill is LDS-only (cheap serial), and the
// element pass is coalesced (consecutive elements = consecutive tmp addrs)
// with 8 independent pipelined rounds, histogram fused in.
// ---------------------------------------------------------------------------
__global__ __launch_bounds__(256) void k_compact(const ushort* __restrict__ scanT,
                                                 const unsigned long long* __restrict__ tmp,
                                                 unsigned long long* __restrict__ csr,
                                                 int* __restrict__ rowptr,
                                                 const int* __restrict__ user_idx,
                                                 int* __restrict__ winner) {
    __shared__ int runstart[NCHUNK];
    __shared__ int pref[NCHUNK + 1];
    __shared__ int sutil[16];
    __shared__ int rcur[RPB];
    __shared__ int obase_s;
    __shared__ unsigned long long stag[CAPB];    // 24 KB
    __shared__ ushort rmap[CAPB];                // 6 KB element->run map
    const int b = blockIdx.x;
    const int t = threadIdx.x;

    if (b == 0) {                                // winner atomicMax side-job
        for (int i = t; i < BATCH; i += 256) atomicMax(&winner[user_idx[i]], i);
    }

    int s0v0, s0v1;
    {
        int r0 = t, r1 = t + 256;
        int a0 = scanT[(size_t)b * NCHUNK + r0];
        int a1 = scanT[(size_t)(b + 1) * NCHUNK + r0];
        int c0 = scanT[(size_t)b * NCHUNK + r1];
        int c1 = scanT[(size_t)(b + 1) * NCHUNK + r1];
        runstart[r0] = r0 * CHUNK + a0;
        runstart[r1] = r1 * CHUNK + c0;
        pref[r0] = a1 - a0;
        pref[r1] = c1 - c0;
        s0v0 = a0; s0v1 = c0;
    }
    if (t < RPB) rcur[t] = 0;
    __syncthreads();

    // obase = Sigma s0 (elements with bucket < b across all chunks)
    {
        int msum = s0v0 + s0v1;
        int mex = block_excl_scan(msum, sutil);
        if (t == 255) obase_s = mex + msum;
    }
    int v0 = pref[t * 2], v1 = pref[t * 2 + 1];
    int sum = v0 + v1;
    int excl = block_excl_scan(sum, sutil);
    pref[t * 2] = excl;
    pref[t * 2 + 1] = excl + v0;
    if (t == 255) pref[NCHUNK] = excl + sum;
    __syncthreads();

    const int total = pref[NCHUNK];
    const int obase = obase_s;

    if (total <= CAPB) {
        // (a) fill element->run map (LDS-only serial loop, no mem latency);
        //     also pre-bias runstart so element addr = runstart[r] + i
        for (int r = t; r < NCHUNK; r += 256) {
            int p0 = pref[r], p1 = pref[r + 1];
            runstart[r] -= p0;
            for (int i = p0; i < p1; ++i) rmap[i] = (ushort)r;
        }
        __syncthreads();
        // (b) element-parallel coalesced staging + fused row histogram
        for (int i = t; i < total; i += 256) {
            int r = rmap[i];
            unsigned long long pk = tmp[runstart[r] + i];
            stag[i] = pk;
            atomicAdd(&rcur[(int)(pk >> 50) & 127], 1);
        }
        __syncthreads();
        int rv = (t < RPB) ? rcur[t] : 0;
        int rex = block_excl_scan(rv, sutil);
        if (t < RPB) {
            rcur[t] = rex;
            int grow = b * RPB + t;
            if (grow < NNODE) rowptr[grow] = obase + rex;
        }
        __syncthreads();
        // scatter (bucket-local region, L2-resident)
        for (int i = t; i < total; i += 256) {
            unsigned long long pk = stag[i];
            int ro = (int)(pk >> 50) & 127;
            int pos = atomicAdd(&rcur[ro], 1);
            csr[obase + pos] = pk;
        }
        return;
    }

    // ---- fallback: binary-search path (runstart unbiased here) ----
    for (int i = t; i < total; i += 256) {
        int lo = 0, hi = NCHUNK - 1;
        while (lo < hi) {
            int mid = (lo + hi + 1) >> 1;
            if (pref[mid] <= i) lo = mid; else hi = mid - 1;
        }
        unsigned long long pk = tmp[runstart[lo] + (i - pref[lo])];
        atomicAdd(&rcur[(int)(pk >> 50) & 127], 1);
    }
    __syncthreads();
    int rv = (t < RPB) ? rcur[t] : 0;
    int rex = block_excl_scan(rv, sutil);
    if (t < RPB) {
        rcur[t] = rex;
        int grow = b * RPB + t;
        if (grow < NNODE) rowptr[grow] = obase + rex;
    }
    __syncthreads();
    for (int i = t; i < total; i += 256) {
        int lo = 0, hi = NCHUNK - 1;
        while (lo < hi) {
            int mid = (lo + hi + 1) >> 1;
            if (pref[mid] <= i) lo = mid; else hi = mid - 1;
        }
        unsigned long long pk = tmp[runstart[lo] + (i - pref[lo])];
        int ro = (int)(pk >> 50) & 127;
        int pos = atomicAdd(&rcur[ro], 1);
        csr[obase + pos] = pk;
    }
}

// ---------------------------------------------------------------------------
// SpMM + A-prep (frozen: R2 concurrency shape + R9/R10 single-round clamp
// ladder + R11 plain stores). At its structural roofline: 0.18 gathers/cyc/CU
// = VMEM-queue x L3-latency bound; cols are uniform-random, no locality left.
// ---------------------------------------------------------------------------
template<int K>
__device__ __forceinline__ float gaccK(const unsigned long long* __restrict__ csr,
                                       const char* __restrict__ EbfB, int lane2,
                                       int j, int m) {
    unsigned long long pk[K];
    float ev[K];
#pragma unroll
    for (int k = 0; k < K; ++k) pk[k] = csr[j + k];             // merged s_loads
#pragma unroll
    for (int k = 0; k < K; ++k) {
        int col = (k < m) ? ((int)(pk[k] >> 32) & 0x3FFFF) : 0; // SALU sel
        ev[k] = bf2f(*(const ushort*)(EbfB + ((size_t)col << 7) + lane2));
    }
    float a = 0.f;
#pragma unroll
    for (int k = 0; k < K; ++k) {
        unsigned v = (k < m) ? (unsigned)pk[k] : 0u;            // SALU sel
        a += __uint_as_float(v) * ev[k];
    }
    return a;
}

__global__ __launch_bounds__(256) void k_spmm(const int* __restrict__ rowptr,
                                              const unsigned long long* __restrict__ csr,
                                              const ushort* __restrict__ Ebf,
                                              ushort* __restrict__ Abf) {
    int lane  = threadIdx.x & 63;
    int lane2 = lane * 2;                               // loop-invariant VGPR
    int row   = blockIdx.x * 4 + (threadIdx.x >> 6);
    row = __builtin_amdgcn_readfirstlane(row);          // force uniform
    if (row >= NNODE) return;
    int s = __builtin_amdgcn_readfirstlane(rowptr[row]);
    int e = __builtin_amdgcn_readfirstlane(rowptr[row + 1]);
    const char* EbfB = (const char*)Ebf;
    float eo = bf2f(Ebf[row * DIM + lane]);             // own E row (independent)
    float acc = 0.f;
    int j = s;
    // drain to <=32 remaining with full-16 rounds (nnz>32: P ~ 1e-4)
    for (; e - j > 32; j += 16) acc += gaccK<16>(csr, EbfB, lane2, j, 16);
    int m = e - j;                                      // uniform 0..32
    if (m > 24)      acc += gaccK<32>(csr, EbfB, lane2, j, m);
    else if (m > 16) acc += gaccK<24>(csr, EbfB, lane2, j, m);
    else if (m > 8)  acc += gaccK<16>(csr, EbfB, lane2, j, m);
    else if (m > 0)  acc += gaccK<8> (csr, EbfB, lane2, j, m);
    Abf[row * 128 + lane]      = f2bf(acc + eo);        // plain store (L2/L3)
    Abf[row * 128 + 64 + lane] = f2bf(acc * eo);        // plain store (L2/L3)
}

// ---------------------------------------------------------------------------
// Transform via MFMA: E_new = leaky_relu(Abf @ Wt^T + b). A rows arrive
// pre-packed bf16 from k_spmm; staging reads are plain loads (L3 hit).
// ---------------------------------------------------------------------------
__global__ __launch_bounds__(256) void k_transform(const ushort* __restrict__ Abf,
                                                   const ushort* __restrict__ Wtg,
                                                   const float* __restrict__ b1k,
                                                   const float* __restrict__ b2k,
                                                   ushort* __restrict__ Ebf_out) {
    __shared__ ushort A_s[64 * 136];        // 17408 B; aliased as C [64][68] f32
    __shared__ ushort W_s[64 * 136];        // 17408 B
    __shared__ float  bias_s[64];

    const int t = threadIdx.x;
    const int rowbase = blockIdx.x * 64;
    if (t < 64) bias_s[t] = b1k[t] + b2k[t];

    // stage Wt: [n][k] k-contiguous (B-fragment order)
#pragma unroll
    for (int it = 0; it < 4; ++it) {
        int task = t + 256 * it;            // 0..1023
        int n = task >> 4, k = (task & 15) * 8;
        uint4 wv = *(const uint4*)&Wtg[n * 128 + k];
        *(uint4*)&W_s[n * 136 + k] = wv;
    }
    // stage A: straight copy of packed rows (plain loads -> L3 hit)
#pragma unroll
    for (int it = 0; it < 4; ++it) {
        int task = t + 256 * it;            // 0..1023
        int rl = task >> 4, k8 = (task & 15) * 8;
        int row = rowbase + rl;
        uintx4 v = {0u, 0u, 0u, 0u};
        if (row < NNODE)
            v = *(const uintx4*)&Abf[row * 128 + k8];
        *(uintx4*)&A_s[rl * 136 + k8] = v;
    }
    __syncthreads();

    const int w = t >> 6, l = t & 63;
    const int m16 = l & 15;                 // row-in-tile (A), col (B/C)
    const int q   = l >> 4;                 // quad
    const int lm  = w * 16 + m16;           // local A row

    f32x4 z = {0.f, 0.f, 0.f, 0.f};
    f32x4 acc[4] = {z, z, z, z};
#pragma unroll
    for (int ks = 0; ks < 4; ++ks) {
        short8 af = *(const short8*)&A_s[lm * 136 + ks * 32 + q * 8];
#pragma unroll
        for (int nt = 0; nt < 4; ++nt) {
            short8 wf = *(const short8*)&W_s[(nt * 16 + m16) * 136 + ks * 32 + q * 8];
            acc[nt] = __builtin_amdgcn_mfma_f32_16x16x32_bf16(af, wf, acc[nt], 0, 0, 0);
        }
    }
    __syncthreads();                        // A_s reads complete

    float* Cs = (float*)A_s;                // [64][68]
#pragma unroll
    for (int nt = 0; nt < 4; ++nt) {
        int col = nt * 16 + m16;
#pragma unroll
        for (int r = 0; r < 4; ++r) {
            int lrow = w * 16 + q * 4 + r;
            Cs[lrow * 68 + col] = acc[nt][r];
        }
    }
    __syncthreads();

#pragma unroll
    for (int it = 0; it < 2; ++it) {
        int task = t + 256 * it;            // 0..511
        int rl = task >> 3, col = (task & 7) * 8;
        int row = rowbase + rl;
        if (row < NNODE) {
            float4 v0 = *(const float4*)&Cs[rl * 68 + col];
            float4 v1 = *(const float4*)&Cs[rl * 68 + col + 4];
            float o[8] = {v0.x, v0.y, v0.z, v0.w, v1.x, v1.y, v1.z, v1.w};
            ushort ob[8];
#pragma unroll
            for (int j = 0; j < 8; ++j) {
                float v = o[j] + bias_s[col + j];
                v = v >= 0.f ? v : 0.2f * v;
                ob[j] = f2bf(v);
            }
            uint4 pb;
            pb.x = (unsigned)ob[0] | ((unsigned)ob[1] << 16);
            pb.y = (unsigned)ob[2] | ((unsigned)ob[3] << 16);
            pb.z = (unsigned)ob[4] | ((unsigned)ob[5] << 16);
            pb.w = (unsigned)ob[6] | ((unsigned)ob[7] << 16);
            *(uint4*)&Ebf_out[row * 64 + col] = pb;
        }
    }
}

// ---------------------------------------------------------------------------
// Gather: one wave per output row-segment; optional row L2-normalization.
// ---------------------------------------------------------------------------
__global__ __launch_bounds__(256) void k_gather(const ushort* __restrict__ Ebf,
                                                const int* __restrict__ user_idx,
                                                const int* __restrict__ pos_idx,
                                                const int* __restrict__ neg_idx,
                                                float* __restrict__ out,
                                                int seg, int normalize) {
    int wid  = threadIdx.x >> 6;
    int lane = threadIdx.x & 63;
    int o = blockIdx.x * 4 + wid;          // 0 .. 3*BATCH-1
    if (o >= 3 * BATCH) return;
    int g = o >> 10, b = o & 1023;
    int row;
    if (g == 0)      row = user_idx[b];
    else if (g == 1) row = N_USERC + pos_idx[b];
    else             row = N_USERC + neg_idx[b];
    float v = bf2f(Ebf[row * DIM + lane]);
    if (normalize) {
        float ss = v * v;
#pragma unroll
        for (int m = 32; m; m >>= 1) ss += __shfl_xor(ss, m, 64);
        float nrm = sqrtf(ss);
        nrm = fmaxf(nrm, 1e-12f);
        v = v / nrm;
    }
    out[(g * BATCH + b) * 256 + seg * 64 + lane] = v;
}

// ---------------------------------------------------------------------------
// launch — 13 nodes
// ---------------------------------------------------------------------------
extern "C" void kernel_launch(void* const* d_in, const int* in_sizes, int n_in,
                              void* d_out, int out_size, void* d_ws, size_t ws_size,
                              hipStream_t stream) {
    const float* user_emb  = (const float*)d_in[0];
    const float* item_emb  = (const float*)d_in[1];
    const float* lin1_w    = (const float*)d_in[2];
    const float* lin1_b    = (const float*)d_in[3];
    const float* lin2_w    = (const float*)d_in[4];
    const float* lin2_b    = (const float*)d_in[5];
    const float* w1        = (const float*)d_in[6];
    const float* b1        = (const float*)d_in[7];
    const float* w2        = (const float*)d_in[8];
    const float* b2        = (const float*)d_in[9];
    const int*   lap_row   = (const int*)d_in[10];
    const int*   lap_col   = (const int*)d_in[11];
    const float* lap_val   = (const float*)d_in[12];
    const int*   user_idx  = (const int*)d_in[13];
    const float* user_feat = (const float*)d_in[14];
    const int*   pos_idx   = (const int*)d_in[15];
    const int*   neg_idx   = (const int*)d_in[16];
    const float* mlp_ratio = (const float*)d_in[17];
    float* out = (float*)d_out;

    // workspace carve-up — byte-identical to the R11 layout that passed.
    size_t off = 0;
    auto carve = [&](size_t bytes) { size_t r = off; off = (off + bytes + 255) & ~(size_t)255; return r; };
    size_t oL      = carve((size_t)NNODE * DIM * 4);              // 38.4MB; Abf; aliases tmp
    size_t oEbf    = carve((size_t)NNODE * DIM * 2);              // 19.2MB
    size_t oCsr    = carve((size_t)NNZC * 8);                     // 19.2MB
    size_t oScan   = carve((size_t)NCHUNK * (NBUCK + 1) * 2);     // 1.2MB; later aliased by Wtg
    size_t oBcnt   = carve((size_t)NBUCK * 4);                    // (kept, unused)
    size_t oBstart = carve((size_t)(NBUCK + 1) * 4);              // (kept, unused)
    size_t oRowptr = carve((size_t)(NNODE + 1) * 4);
    size_t oWinner = carve((size_t)N_USERC * 4);
    size_t oBcntP  = carve((size_t)NPARTB * NBUCK * 4);           // (kept, unused)
    (void)ws_size; (void)oBcnt; (void)oBstart; (void)oBcntP;

    char* base = (char*)d_ws;
    ushort*             Abf    = (ushort*)(base + oL);
    unsigned long long* tmp    = (unsigned long long*)(base + oL);   // alias
    ushort*             Ebf    = (ushort*)(base + oEbf);
    unsigned long long* csr    = (unsigned long long*)(base + oCsr);
    ushort*             scanT  = (ushort*)(base + oScan);
    int*                rowptr = (int*)(base + oRowptr);
    int*                winner = (int*)(base + oWinner);
    ushort*             Wtg    = (ushort*)(base + oScan);            // alias (48KB << 1.2MB)

    // --- partition build ---
    k_chunksort<<<NCHUNK, 256, 0, stream>>>(lap_row, lap_col, lap_val, tmp, scanT, winner);
    k_compact<<<NBUCK, 256, 0, stream>>>(scanT, tmp, csr, rowptr, user_idx, winner);

    // --- merged prep (AFTER compact: Wtg overwrites scanT; winner final) ---
    k_prep<<<(NNODE * DIM / 4 + 255) / 256, 256, 0, stream>>>(
        user_emb, item_emb, Ebf, w1, w2, Wtg,
        user_feat, lin1_w, lin1_b, lin2_w, lin2_b, mlp_ratio, winner, rowptr);
    k_gather<<<(3 * BATCH) / 4, 256, 0, stream>>>(Ebf, user_idx, pos_idx, neg_idx, out, 0, 0);

    // --- layers ---
    for (int k = 0; k < NLAYERS; ++k) {
        k_spmm<<<(NNODE + 3) / 4, 256, 0, stream>>>(rowptr, csr, Ebf, Abf);
        k_transform<<<(NNODE + 63) / 64, 256, 0, stream>>>(
            Abf, Wtg + (size_t)k * 64 * 128, b1 + (size_t)k * DIM,
            b2 + (size_t)k * DIM, Ebf);
        k_gather<<<(3 * BATCH) / 4, 256, 0, stream>>>(Ebf, user_idx, pos_idx, neg_idx,
                                                      out, k + 1, 1);
    }
}

// Round 13
// 393.557 us; speedup vs baseline: 1.0121x; 1.0121x over previous
//
#include <hip/hip_runtime.h>
#include <hip/hip_bf16.h>

#define N_USERC 50000
#define N_ITEMC 100000
#define NNODE   150000
#define DIM     64
#define NLAYERS 3
#define NNZC    2400000
#define BATCH   1024

#define RPB     128                 // rows per bucket (bucket = row>>7)
#define NBUCK   1172                // ceil(150000/128)
#define NCHUNK  1024                // R13: halved chunks -> 2x chunksort occupancy
#define CHUNK   2344                // 1024*2344 = 2400256 >= NNZ
#define CAPB    3072                // compact LDS staging capacity (avg 2048)
#define NPARTB  8                   // (carve kept for layout stability)

using short8 = __attribute__((ext_vector_type(8))) short;   // 8 bf16
using f32x4  = __attribute__((ext_vector_type(4))) float;   // MFMA acc
using uintx4 = __attribute__((ext_vector_type(4))) unsigned;

// ---------------------------------------------------------------------------
// helpers
// ---------------------------------------------------------------------------
__device__ __forceinline__ float bf2f(ushort u) {
    return __uint_as_float(((unsigned)u) << 16);
}
__device__ __forceinline__ ushort f2bf(float f) {
    unsigned u = __float_as_uint(f);
    u += 0x7FFF + ((u >> 16) & 1);          // RNE
    return (ushort)(u >> 16);
}

// exclusive scan of one value per thread across the block (blockDim==256)
__device__ __forceinline__ int block_excl_scan(int v, int* lds) {
    int lane = threadIdx.x & 63;
    int wid  = threadIdx.x >> 6;
    int nw   = (blockDim.x + 63) >> 6;
    int inc = v;
#pragma unroll
    for (int o = 1; o < 64; o <<= 1) {
        int n = __shfl_up(inc, o, 64);
        if (lane >= o) inc += n;
    }
    if (lane == 63) lds[wid] = inc;
    __syncthreads();
    if (wid == 0) {
        int tv = (lane < nw) ? lds[lane] : 0;
#pragma unroll
        for (int o = 1; o < 16; o <<= 1) {
            int n = __shfl_up(tv, o, 64);
            if (lane >= o) tv += n;
        }
        if (lane < nw) lds[lane] = tv;
    }
    __syncthreads();
    int woff = (wid == 0) ? 0 : lds[wid - 1];
    return woff + (inc - v);
}

// ---------------------------------------------------------------------------
// Merged prep: copy_E + INLINE user-MLP blend + prepW. winner[] inited in
// chunksort, atomicMax'd in compact (both prior dispatches). Also writes
// rowptr[NNODE]=NNZC.
// ---------------------------------------------------------------------------
__global__ __launch_bounds__(256) void k_prep(const float* __restrict__ ue,
                                              const float* __restrict__ ie,
                                              ushort* __restrict__ Ebf,
                                              const float* __restrict__ w1,
                                              const float* __restrict__ w2,
                                              ushort* __restrict__ Wtg,
                                              const float* __restrict__ user_feat,
                                              const float* __restrict__ l1w,
                                              const float* __restrict__ l1b,
                                              const float* __restrict__ l2w,
                                              const float* __restrict__ l2b,
                                              const float* __restrict__ ratio_p,
                                              const int* __restrict__ winner,
                                              int* __restrict__ rowptr) {
    int i = blockIdx.x * blockDim.x + threadIdx.x;        // float4 index
    const int userEnd = N_USERC * DIM / 4;
    const int total   = NNODE * DIM / 4;
    if (i == 0) rowptr[NNODE] = NNZC;
    if (i < total) {
        float4 v;
        if (i < userEnd) v = ((const float4*)ue)[i];
        else             v = ((const float4*)ie)[i - userEnd];
        if (i < userEnd) {
            int u = i >> 4;
            int b = winner[u];
            if (b >= 0) {                                  // blend with MLP out
                int d0 = (i & 15) * 4;
                float ratio = ratio_p[0];
                float uf0 = user_feat[b * 4 + 0], uf1 = user_feat[b * 4 + 1];
                float uf2 = user_feat[b * 4 + 2], uf3 = user_feat[b * 4 + 3];
                float a0 = l2b[d0 + 0], a1 = l2b[d0 + 1];
                float a2 = l2b[d0 + 2], a3 = l2b[d0 + 3];
#pragma unroll
                for (int j = 0; j < 32; ++j) {
                    float h = l1b[j] + uf0 * l1w[0 * 32 + j] + uf1 * l1w[1 * 32 + j]
                                     + uf2 * l1w[2 * 32 + j] + uf3 * l1w[3 * 32 + j];
                    a0 += h * l2w[j * DIM + d0 + 0];
                    a1 += h * l2w[j * DIM + d0 + 1];
                    a2 += h * l2w[j * DIM + d0 + 2];
                    a3 += h * l2w[j * DIM + d0 + 3];
                }
                float om = 1.f - ratio;
                v.x = v.x * om + a0 * ratio;
                v.y = v.y * om + a1 * ratio;
                v.z = v.z * om + a2 * ratio;
                v.w = v.w * om + a3 * ratio;
            }
        }
        ushort4 b4;
        b4.x = f2bf(v.x); b4.y = f2bf(v.y); b4.z = f2bf(v.z); b4.w = f2bf(v.w);
        ((ushort4*)Ebf)[i] = b4;
    }
    if (i < NLAYERS * 64 * 128) {                         // blocks 0..95
        int layer = i >> 13;                              // /8192
        int rem = i & 8191;
        int n = rem >> 7, kk = rem & 127;
        float v = (kk < 64) ? w1[layer * 4096 + kk * 64 + n]
                            : w2[layer * 4096 + (kk - 64) * 64 + n];
        Wtg[i] = f2bf(v);
    }
}

// ---------------------------------------------------------------------------
// Pass 1: per-chunk LDS counting sort into 128-row buckets. Streaming writes.
// packed = [ ro:7 (bits 50..56) | col:18 (bits 32..49) | val:32 ]
// R13: CHUNK halved (2344) -> LDS 23.5KB -> 6 blocks/CU (was 3) = 2x TLP
// for the latency-bound stream+scatter phases. Publishes offsets TRANSPOSED:
// scanT[bucket][chunk]; row NBUCK = totals. Also initializes winner[].
// ---------------------------------------------------------------------------
__global__ __launch_bounds__(256) void k_chunksort(const int* __restrict__ rows,
                                                   const int* __restrict__ cols,
                                                   const float* __restrict__ vals,
                                                   unsigned long long* __restrict__ tmp,
                                                   ushort* __restrict__ scanT,
                                                   int* __restrict__ winner) {
    __shared__ int hist[NBUCK];                 // hist -> excl scan -> cursors
    __shared__ int sutil[16];
    __shared__ unsigned long long stag[CHUNK];  // 18.75 KB

    const int c = blockIdx.x;
    const int s = c * CHUNK;
    const int e = (s + CHUNK < NNZC) ? s + CHUNK : NNZC;
    const int t = threadIdx.x;

    // winner init (consumed by k_compact's atomicMax, a later dispatch)
    for (int i = c * 256 + t; i < N_USERC; i += NCHUNK * 256) winner[i] = -1;

    for (int i = t; i < NBUCK; i += 256) hist[i] = 0;
    __syncthreads();
    for (int i = s + t; i < e; i += 256) atomicAdd(&hist[rows[i] >> 7], 1);
    __syncthreads();

    // scan 1172 counters: 5 entries per thread
    int loc[5];
    int sum = 0;
#pragma unroll
    for (int k = 0; k < 5; ++k) {
        int idx = t * 5 + k;
        int v = (idx < NBUCK) ? hist[idx] : 0;
        loc[k] = sum;
        sum += v;
    }
    int excl = block_excl_scan(sum, sutil);
#pragma unroll
    for (int k = 0; k < 5; ++k) {
        int idx = t * 5 + k;
        if (idx < NBUCK) hist[idx] = excl + loc[k];
    }
    __syncthreads();

    // publish per-chunk offsets (exclusive) TRANSPOSED; totals in row NBUCK
    for (int i = t; i < NBUCK; i += 256) scanT[(size_t)i * NCHUNK + c] = (ushort)hist[i];
    if (t == 0) scanT[(size_t)NBUCK * NCHUNK + c] = (ushort)(e - s);
    __syncthreads();

    // scatter into LDS staging via cursors
    for (int i = s + t; i < e; i += 256) {
        int r = rows[i];
        int b = r >> 7, ro = r & 127;
        unsigned hi = ((unsigned)ro << 18) | (unsigned)cols[i];
        unsigned long long pk = ((unsigned long long)hi << 32) | (unsigned)__float_as_uint(vals[i]);
        int pos = atomicAdd(&hist[b], 1);
        stag[pos] = pk;
    }
    __syncthreads();

    // streaming write-back (full lines)
    int n = e - s;
    for (int i = t; i < n; i += 256) tmp[s + i] = stag[i];
}

// Pass 2: compact runs into bucket-contiguous, ROW-SORTED csr + rowptr.
// obase computed IN-BLOCK: Sigma_c scanT[b][c]. Block 0 also does the
// winner atomicMax side-job. Staging is element-parallel via the LDS
// run-map (R12). R13: 4 runs per thread (NCHUNK=1024).
// ---------------------------------------------------------------------------
__global__ __launch_bounds__(256) void k_compact(const ushort* __restrict__ scanT,
                                                 const unsigned long long* __restrict__ tmp,
                                                 unsigned long long* __restrict__ csr,
                                                 int* __restrict__ rowptr,
                                                 const int* __restrict__ user_idx,
                                                 int* __restrict__ winner) {
    __shared__ int runstart[NCHUNK];             // 4 KB
    __shared__ int pref[NCHUNK + 1];             // 4 KB
    __shared__ int sutil[16];
    __shared__ int rcur[RPB];
    __shared__ int obase_s;
    __shared__ unsigned long long stag[CAPB];    // 24 KB
    __shared__ ushort rmap[CAPB];                // 6 KB element->run map
    const int b = blockIdx.x;
    const int t = threadIdx.x;

    if (b == 0) {                                // winner atomicMax side-job
        for (int i = t; i < BATCH; i += 256) atomicMax(&winner[user_idx[i]], i);
    }

    int s0q[4];
#pragma unroll
    for (int q = 0; q < 4; ++q) {                // 4 runs per thread
        int r = t + 256 * q;
        int a0 = scanT[(size_t)b * NCHUNK + r];
        int a1 = scanT[(size_t)(b + 1) * NCHUNK + r];
        runstart[r] = r * CHUNK + a0;
        pref[r] = a1 - a0;
        s0q[q] = a0;
    }
    if (t < RPB) rcur[t] = 0;
    __syncthreads();

    // obase = Sigma s0 (elements with bucket < b across all chunks)
    {
        int msum = s0q[0] + s0q[1] + s0q[2] + s0q[3];
        int mex = block_excl_scan(msum, sutil);
        if (t == 255) obase_s = mex + msum;
    }
    // pref scan: 4 consecutive runs per thread
    int v0 = pref[t * 4], v1 = pref[t * 4 + 1];
    int v2 = pref[t * 4 + 2], v3 = pref[t * 4 + 3];
    int sum = v0 + v1 + v2 + v3;
    int excl = block_excl_scan(sum, sutil);
    pref[t * 4]     = excl;
    pref[t * 4 + 1] = excl + v0;
    pref[t * 4 + 2] = excl + v0 + v1;
    pref[t * 4 + 3] = excl + v0 + v1 + v2;
    if (t == 255) pref[NCHUNK] = excl + sum;
    __syncthreads();

    const int total = pref[NCHUNK];
    const int obase = obase_s;

    if (total <= CAPB) {
        // (a) fill element->run map (LDS-only); pre-bias runstart
        for (int r = t; r < NCHUNK; r += 256) {
            int p0 = pref[r], p1 = pref[r + 1];
            runstart[r] -= p0;
            for (int i = p0; i < p1; ++i) rmap[i] = (ushort)r;
        }
        __syncthreads();
        // (b) element-parallel coalesced staging + fused row histogram
        for (int i = t; i < total; i += 256) {
            int r = rmap[i];
            unsigned long long pk = tmp[runstart[r] + i];
            stag[i] = pk;
            atomicAdd(&rcur[(int)(pk >> 50) & 127], 1);
        }
        __syncthreads();
        int rv = (t < RPB) ? rcur[t] : 0;
        int rex = block_excl_scan(rv, sutil);
        if (t < RPB) {
            rcur[t] = rex;
            int grow = b * RPB + t;
            if (grow < NNODE) rowptr[grow] = obase + rex;
        }
        __syncthreads();
        // scatter (bucket-local region, L2-resident)
        for (int i = t; i < total; i += 256) {
            unsigned long long pk = stag[i];
            int ro = (int)(pk >> 50) & 127;
            int pos = atomicAdd(&rcur[ro], 1);
            csr[obase + pos] = pk;
        }
        return;
    }

    // ---- fallback: binary-search path (runstart unbiased here) ----
    for (int i = t; i < total; i += 256) {
        int lo = 0, hi = NCHUNK - 1;
        while (lo < hi) {
            int mid = (lo + hi + 1) >> 1;
            if (pref[mid] <= i) lo = mid; else hi = mid - 1;
        }
        unsigned long long pk = tmp[runstart[lo] + (i - pref[lo])];
        atomicAdd(&rcur[(int)(pk >> 50) & 127], 1);
    }
    __syncthreads();
    int rv = (t < RPB) ? rcur[t] : 0;
    int rex = block_excl_scan(rv, sutil);
    if (t < RPB) {
        rcur[t] = rex;
        int grow = b * RPB + t;
        if (grow < NNODE) rowptr[grow] = obase + rex;
    }
    __syncthreads();
    for (int i = t; i < total; i += 256) {
        int lo = 0, hi = NCHUNK - 1;
        while (lo < hi) {
            int mid = (lo + hi + 1) >> 1;
            if (pref[mid] <= i) lo = mid; else hi = mid - 1;
        }
        unsigned long long pk = tmp[runstart[lo] + (i - pref[lo])];
        int ro = (int)(pk >> 50) & 127;
        int pos = atomicAdd(&rcur[ro], 1);
        csr[obase + pos] = pk;
    }
}

// ---------------------------------------------------------------------------
// SpMM + A-prep (frozen: R2 concurrency shape + R9/R10 single-round clamp
// ladder + R11 plain stores). At its structural roofline: 0.18 gathers/cyc/CU
// = VMEM-queue x L3-latency bound; cols are uniform-random, no locality left.
// ---------------------------------------------------------------------------
template<int K>
__device__ __forceinline__ float gaccK(const unsigned long long* __restrict__ csr,
                                       const char* __restrict__ EbfB, int lane2,
                                       int j, int m) {
    unsigned long long pk[K];
    float ev[K];
#pragma unroll
    for (int k = 0; k < K; ++k) pk[k] = csr[j + k];             // merged s_loads
#pragma unroll
    for (int k = 0; k < K; ++k) {
        int col = (k < m) ? ((int)(pk[k] >> 32) & 0x3FFFF) : 0; // SALU sel
        ev[k] = bf2f(*(const ushort*)(EbfB + ((size_t)col << 7) + lane2));
    }
    float a = 0.f;
#pragma unroll
    for (int k = 0; k < K; ++k) {
        unsigned v = (k < m) ? (unsigned)pk[k] : 0u;            // SALU sel
        a += __uint_as_float(v) * ev[k];
    }
    return a;
}

__global__ __launch_bounds__(256) void k_spmm(const int* __restrict__ rowptr,
                                              const unsigned long long* __restrict__ csr,
                                              const ushort* __restrict__ Ebf,
                                              ushort* __restrict__ Abf) {
    int lane  = threadIdx.x & 63;
    int lane2 = lane * 2;                               // loop-invariant VGPR
    int row   = blockIdx.x * 4 + (threadIdx.x >> 6);
    row = __builtin_amdgcn_readfirstlane(row);          // force uniform
    if (row >= NNODE) return;
    int s = __builtin_amdgcn_readfirstlane(rowptr[row]);
    int e = __builtin_amdgcn_readfirstlane(rowptr[row + 1]);
    const char* EbfB = (const char*)Ebf;
    float eo = bf2f(Ebf[row * DIM + lane]);             // own E row (independent)
    float acc = 0.f;
    int j = s;
    // drain to <=32 remaining with full-16 rounds (nnz>32: P ~ 1e-4)
    for (; e - j > 32; j += 16) acc += gaccK<16>(csr, EbfB, lane2, j, 16);
    int m = e - j;                                      // uniform 0..32
    if (m > 24)      acc += gaccK<32>(csr, EbfB, lane2, j, m);
    else if (m > 16) acc += gaccK<24>(csr, EbfB, lane2, j, m);
    else if (m > 8)  acc += gaccK<16>(csr, EbfB, lane2, j, m);
    else if (m > 0)  acc += gaccK<8> (csr, EbfB, lane2, j, m);
    Abf[row * 128 + lane]      = f2bf(acc + eo);        // plain store (L2/L3)
    Abf[row * 128 + 64 + lane] = f2bf(acc * eo);        // plain store (L2/L3)
}

// ---------------------------------------------------------------------------
// Transform via MFMA: E_new = leaky_relu(Abf @ Wt^T + b). A rows arrive
// pre-packed bf16 from k_spmm; staging reads are plain loads (L3 hit).
// ---------------------------------------------------------------------------
__global__ __launch_bounds__(256) void k_transform(const ushort* __restrict__ Abf,
                                                   const ushort* __restrict__ Wtg,
                                                   const float* __restrict__ b1k,
                                                   const float* __restrict__ b2k,
                                                   ushort* __restrict__ Ebf_out) {
    __shared__ ushort A_s[64 * 136];        // 17408 B; aliased as C [64][68] f32
    __shared__ ushort W_s[64 * 136];        // 17408 B
    __shared__ float  bias_s[64];

    const int t = threadIdx.x;
    const int rowbase = blockIdx.x * 64;
    if (t < 64) bias_s[t] = b1k[t] + b2k[t];

    // stage Wt: [n][k] k-contiguous (B-fragment order)
#pragma unroll
    for (int it = 0; it < 4; ++it) {
        int task = t + 256 * it;            // 0..1023
        int n = task >> 4, k = (task & 15) * 8;
        uint4 wv = *(const uint4*)&Wtg[n * 128 + k];
        *(uint4*)&W_s[n * 136 + k] = wv;
    }
    // stage A: straight copy of packed rows (plain loads -> L3 hit)
#pragma unroll
    for (int it = 0; it < 4; ++it) {
        int task = t + 256 * it;            // 0..1023
        int rl = task >> 4, k8 = (task & 15) * 8;
        int row = rowbase + rl;
        uintx4 v = {0u, 0u, 0u, 0u};
        if (row < NNODE)
            v = *(const uintx4*)&Abf[row * 128 + k8];
        *(uintx4*)&A_s[rl * 136 + k8] = v;
    }
    __syncthreads();

    const int w = t >> 6, l = t & 63;
    const int m16 = l & 15;                 // row-in-tile (A), col (B/C)
    const int q   = l >> 4;                 // quad
    const int lm  = w * 16 + m16;           // local A row

    f32x4 z = {0.f, 0.f, 0.f, 0.f};
    f32x4 acc[4] = {z, z, z, z};
#pragma unroll
    for (int ks = 0; ks < 4; ++ks) {
        short8 af = *(const short8*)&A_s[lm * 136 + ks * 32 + q * 8];
#pragma unroll
        for (int nt = 0; nt < 4; ++nt) {
            short8 wf = *(const short8*)&W_s[(nt * 16 + m16) * 136 + ks * 32 + q * 8];
            acc[nt] = __builtin_amdgcn_mfma_f32_16x16x32_bf16(af, wf, acc[nt], 0, 0, 0);
        }
    }
    __syncthreads();                        // A_s reads complete

    float* Cs = (float*)A_s;                // [64][68]
#pragma unroll
    for (int nt = 0; nt < 4; ++nt) {
        int col = nt * 16 + m16;
#pragma unroll
        for (int r = 0; r < 4; ++r) {
            int lrow = w * 16 + q * 4 + r;
            Cs[lrow * 68 + col] = acc[nt][r];
        }
    }
    __syncthreads();

#pragma unroll
    for (int it = 0; it < 2; ++it) {
        int task = t + 256 * it;            // 0..511
        int rl = task >> 3, col = (task & 7) * 8;
        int row = rowbase + rl;
        if (row < NNODE) {
            float4 v0 = *(const float4*)&Cs[rl * 68 + col];
            float4 v1 = *(const float4*)&Cs[rl * 68 + col + 4];
            float o[8] = {v0.x, v0.y, v0.z, v0.w, v1.x, v1.y, v1.z, v1.w};
            ushort ob[8];
#pragma unroll
            for (int j = 0; j < 8; ++j) {
                float v = o[j] + bias_s[col + j];
                v = v >= 0.f ? v : 0.2f * v;
                ob[j] = f2bf(v);
            }
            uint4 pb;
            pb.x = (unsigned)ob[0] | ((unsigned)ob[1] << 16);
            pb.y = (unsigned)ob[2] | ((unsigned)ob[3] << 16);
            pb.z = (unsigned)ob[4] | ((unsigned)ob[5] << 16);
            pb.w = (unsigned)ob[6] | ((unsigned)ob[7] << 16);
            *(uint4*)&Ebf_out[row * 64 + col] = pb;
        }
    }
}

// ---------------------------------------------------------------------------
// Gather: one wave per output row-segment; optional row L2-normalization.
// ---------------------------------------------------------------------------
__global__ __launch_bounds__(256) void k_gather(const ushort* __restrict__ Ebf,
                                                const int* __restrict__ user_idx,
                                                const int* __restrict__ pos_idx,
                                                const int* __restrict__ neg_idx,
                                                float* __restrict__ out,
                                                int seg, int normalize) {
    int wid  = threadIdx.x >> 6;
    int lane = threadIdx.x & 63;
    int o = blockIdx.x * 4 + wid;          // 0 .. 3*BATCH-1
    if (o >= 3 * BATCH) return;
    int g = o >> 10, b = o & 1023;
    int row;
    if (g == 0)      row = user_idx[b];
    else if (g == 1) row = N_USERC + pos_idx[b];
    else             row = N_USERC + neg_idx[b];
    float v = bf2f(Ebf[row * DIM + lane]);
    if (normalize) {
        float ss = v * v;
#pragma unroll
        for (int m = 32; m; m >>= 1) ss += __shfl_xor(ss, m, 64);
        float nrm = sqrtf(ss);
        nrm = fmaxf(nrm, 1e-12f);
        v = v / nrm;
    }
    out[(g * BATCH + b) * 256 + seg * 64 + lane] = v;
}

// ---------------------------------------------------------------------------
// launch — 13 nodes
// ---------------------------------------------------------------------------
extern "C" void kernel_launch(void* const* d_in, const int* in_sizes, int n_in,
                              void* d_out, int out_size, void* d_ws, size_t ws_size,
                              hipStream_t stream) {
    const float* user_emb  = (const float*)d_in[0];
    const float* item_emb  = (const float*)d_in[1];
    const float* lin1_w    = (const float*)d_in[2];
    const float* lin1_b    = (const float*)d_in[3];
    const float* lin2_w    = (const float*)d_in[4];
    const float* lin2_b    = (const float*)d_in[5];
    const float* w1        = (const float*)d_in[6];
    const float* b1        = (const float*)d_in[7];
    const float* w2        = (const float*)d_in[8];
    const float* b2        = (const float*)d_in[9];
    const int*   lap_row   = (const int*)d_in[10];
    const int*   lap_col   = (const int*)d_in[11];
    const float* lap_val   = (const float*)d_in[12];
    const int*   user_idx  = (const int*)d_in[13];
    const float* user_feat = (const float*)d_in[14];
    const int*   pos_idx   = (const int*)d_in[15];
    const int*   neg_idx   = (const int*)d_in[16];
    const float* mlp_ratio = (const float*)d_in[17];
    float* out = (float*)d_out;

    // workspace carve-up — same order as R12; oScan grows to 2.4MB with
    // NCHUNK=1024 (Wtg alias still 48KB << 2.4MB).
    size_t off = 0;
    auto carve = [&](size_t bytes) { size_t r = off; off = (off + bytes + 255) & ~(size_t)255; return r; };
    size_t oL      = carve((size_t)NNODE * DIM * 4);              // 38.4MB; Abf; aliases tmp
    size_t oEbf    = carve((size_t)NNODE * DIM * 2);              // 19.2MB
    size_t oCsr    = carve((size_t)NNZC * 8);                     // 19.2MB
    size_t oScan   = carve((size_t)NCHUNK * (NBUCK + 1) * 2);     // 2.4MB; later aliased by Wtg
    size_t oBcnt   = carve((size_t)NBUCK * 4);                    // (kept, unused)
    size_t oBstart = carve((size_t)(NBUCK + 1) * 4);              // (kept, unused)
    size_t oRowptr = carve((size_t)(NNODE + 1) * 4);
    size_t oWinner = carve((size_t)N_USERC * 4);
    size_t oBcntP  = carve((size_t)NPARTB * NBUCK * 4);           // (kept, unused)
    (void)ws_size; (void)oBcnt; (void)oBstart; (void)oBcntP;

    char* base = (char*)d_ws;
    ushort*             Abf    = (ushort*)(base + oL);
    unsigned long long* tmp    = (unsigned long long*)(base + oL);   // alias
    ushort*             Ebf    = (ushort*)(base + oEbf);
    unsigned long long* csr    = (unsigned long long*)(base + oCsr);
    ushort*             scanT  = (ushort*)(base + oScan);
    int*                rowptr = (int*)(base + oRowptr);
    int*                winner = (int*)(base + oWinner);
    ushort*             Wtg    = (ushort*)(base + oScan);            // alias (48KB << 2.4MB)

    // --- partition build ---
    k_chunksort<<<NCHUNK, 256, 0, stream>>>(lap_row, lap_col, lap_val, tmp, scanT, winner);
    k_compact<<<NBUCK, 256, 0, stream>>>(scanT, tmp, csr, rowptr, user_idx, winner);

    // --- merged prep (AFTER compact: Wtg overwrites scanT; winner final) ---
    k_prep<<<(NNODE * DIM / 4 + 255) / 256, 256, 0, stream>>>(
        user_emb, item_emb, Ebf, w1, w2, Wtg,
        user_feat, lin1_w, lin1_b, lin2_w, lin2_b, mlp_ratio, winner, rowptr);
    k_gather<<<(3 * BATCH) / 4, 256, 0, stream>>>(Ebf, user_idx, pos_idx, neg_idx, out, 0, 0);

    // --- layers ---
    for (int k = 0; k < NLAYERS; ++k) {
        k_spmm<<<(NNODE + 3) / 4, 256, 0, stream>>>(rowptr, csr, Ebf, Abf);
        k_transform<<<(NNODE + 63) / 64, 256, 0, stream>>>(
            Abf, Wtg + (size_t)k * 64 * 128, b1 + (size_t)k * DIM,
            b2 + (size_t)k * DIM, Ebf);
        k_gather<<<(3 * BATCH) / 4, 256, 0, stream>>>(Ebf, user_idx, pos_idx, neg_idx,
                                                      out, k + 1, 1);
    }
}